// Round 8
// baseline (201.624 us; speedup 1.0000x reference)
//
#include <hip/hip_runtime.h>
#include <hip/hip_fp16.h>

typedef unsigned long long ull;
typedef unsigned short ushort_t;
typedef unsigned int u32;
typedef short bf16x8 __attribute__((ext_vector_type(8)));
typedef _Float16 f16x8 __attribute__((ext_vector_type(8)));
typedef float f32x4 __attribute__((ext_vector_type(4)));

#define NC 10000   // H*W cells
#define D_ 256     // input dim
#define B_ 1024    // batch
#define W_ 100     // grid width
#define NT 79      // score c-tiles (128 cells each)
#define PKS 160    // pkt row stride in ull
#define TAU 0.10f  // >= 2*eps_score for fp16-input MFMA scores (proven R7)

// async global->LDS, 16B per lane; LDS dest = wave-uniform base + lane*16
__device__ __forceinline__ void gl_lds16(const void* g, void* l) {
    __builtin_amdgcn_global_load_lds(
        (const __attribute__((address_space(1))) u32*)g,
        (__attribute__((address_space(3))) u32*)l,
        16, 0, 0);
}

// bijective XCD-chunk swizzle (m204)
__device__ __forceinline__ int xcd_swz(int orig, int nwg) {
    int q = nwg >> 3, r = nwg & 7;
    int xcd = orig & 7, off = orig >> 3;
    return (xcd < r ? xcd * (q + 1) : r * (q + 1) + (xcd - r) * q) + off;
}

// monotonic float -> sortable uint mapping
__device__ __forceinline__ unsigned fkey(float f) {
    unsigned u = __float_as_uint(f);
    return (u & 0x80000000u) ? ~u : (u | 0x80000000u);
}
__device__ __forceinline__ float unfkey(unsigned k) {
    unsigned u = (k & 0x80000000u) ? (k ^ 0x80000000u) : ~k;
    return __uint_as_float(u);
}

// exact RNE float -> bf16 bits
__device__ __forceinline__ ushort_t f2bf(float f) {
    unsigned u = __float_as_uint(f);
    unsigned r = (u + 0x7fffu + ((u >> 16) & 1u)) >> 16;
    return (ushort_t)r;
}

__device__ __forceinline__ void decay_params(const int* ep, const int* tp, float& lr, float& inv2r2) {
    double decay = 1.0 - (double)(*ep) / (double)(*tp);
    lr = (float)(0.5 * decay);
    float radius = (float)(50.0 * decay);
    inv2r2 = 1.0f / (2.0f * radius * radius);
}

// sorted-pair merge: (a1,a2) <- two smallest of {a1,a2,c1,c2}  (a1<=a2, c1<=c2)
__device__ __forceinline__ void merge2(ull& a1, ull& a2, ull c1, ull c2) {
    ull m1 = a1 < c1 ? a1 : c1;
    ull hi = a1 < c1 ? c1 : a1;
    ull lo2 = a2 < c2 ? a2 : c2;
    a2 = hi < lo2 ? hi : lo2;
    a1 = m1;
}

// fused prep: blocks [0,2500) = w -> wh fp16 + wnorm; blocks [2500,2564) = x -> xh fp16 + xhT bf16
__global__ __launch_bounds__(256) void k_prep(const float* __restrict__ w, const float* __restrict__ x,
                                              __half* __restrict__ wh, float* __restrict__ wnorm,
                                              __half* __restrict__ xh, ushort_t* __restrict__ xhT) {
    int bid = blockIdx.x;
    int tid = threadIdx.x;
    if (bid < NC / 4) {
        int cell = bid * 4 + (tid >> 6);
        int lane = tid & 63;
        float4 v = *reinterpret_cast<const float4*>(&w[(size_t)cell * D_ + lane * 4]);
        float s = v.x * v.x + v.y * v.y + v.z * v.z + v.w * v.w;
        __half hb[4];
        float e[4] = {v.x, v.y, v.z, v.w};
        #pragma unroll
        for (int i = 0; i < 4; ++i) hb[i] = __float2half(e[i]);
        *reinterpret_cast<uint2*>(&wh[(size_t)cell * D_ + lane * 4]) = *reinterpret_cast<uint2*>(hb);
        #pragma unroll
        for (int off = 32; off; off >>= 1) s += __shfl_xor(s, off);
        if (lane == 0) wnorm[cell] = s;
    } else {
        __shared__ ushort_t tile[64][65];
        int idx = bid - NC / 4;
        int b0 = (idx & 15) * 64, d0 = (idx >> 4) * 64;
        #pragma unroll
        for (int r = 0; r < 16; ++r) {
            int f = r * 256 + tid;
            int i = f >> 6, j = f & 63;       // i = b-local, j = d-local
            float v = x[(size_t)(b0 + i) * D_ + d0 + j];
            xh[(size_t)(b0 + i) * D_ + d0 + j] = __float2half(v);
            tile[j][i] = f2bf(v);
        }
        __syncthreads();
        #pragma unroll
        for (int r = 0; r < 2; ++r) {
            int f = r * 256 + tid;            // [0,512): 64 d-rows x 8 units
            int row = f >> 3, u = f & 7;
            ushort_t v[8];
            #pragma unroll
            for (int e = 0; e < 8; ++e) v[e] = tile[row][u * 8 + e];
            *reinterpret_cast<uint4*>(&xhT[(size_t)(d0 + row) * B_ + b0 + u * 8]) =
                *reinterpret_cast<uint4*>(v);
        }
    }
}

// fp16 scores GEMM with fused per-tile (min1,min2) epilogue -> pkt[b][tile]
// tile 128 cells x 128 batch, BK=64, 8 waves (2 cell x 4 batch)
// SINGLE-buffer staging (R5-proven loop: stage, barrier, compute)
__global__ __launch_bounds__(512) void k_scores_mfma(const __half* __restrict__ wh, const __half* __restrict__ xh,
                                                     const float* __restrict__ wnorm, ull* __restrict__ pkt) {
    __shared__ __align__(16) __half As[128 * 64];  // cells x k  (16KB)
    __shared__ __align__(16) __half Bs[128 * 64];  // batch x k  (16KB)
    const int tid = threadIdx.x;
    int orig = blockIdx.y * gridDim.x + blockIdx.x;
    int wgid = xcd_swz(orig, 8 * NT);
    const int b0 = (wgid & 7) * 128;
    const int c0 = (wgid >> 3) * 128;
    const int tile = wgid >> 3;
    const int wid = tid >> 6, lane = tid & 63;
    const int wc = wid >> 2;           // 0..1 -> 64 cells
    const int wb = wid & 3;            // 0..3 -> 32 batch
    const int g4 = lane >> 4, l16 = lane & 15;

    f32x4 acc[4][2] = {};

    for (int k0 = 0; k0 < D_; k0 += 64) {
        if (k0) __syncthreads();
        #pragma unroll
        for (int r = 0; r < 2; ++r) {
            int f = tid + r * 512;        // [0,1024): 128 rows x 8 16B-units
            int row = f >> 3, u = f & 7;
            int ug = (u ^ (row & 7)) * 8;
            int cc = c0 + row; if (cc > NC - 1) cc = NC - 1;
            gl_lds16(&wh[(size_t)cc * D_ + k0 + ug], &As[(f & ~63) * 8]);
            gl_lds16(&xh[(size_t)(b0 + row) * D_ + k0 + ug], &Bs[(f & ~63) * 8]);
        }
        __syncthreads();
        #pragma unroll
        for (int kh = 0; kh < 2; ++kh) {
            int ubase = kh * 4 + g4;
            f16x8 bfr[2];
            #pragma unroll
            for (int fn = 0; fn < 2; ++fn) {
                int rowb = wb * 32 + fn * 16 + l16;
                bfr[fn] = *reinterpret_cast<const f16x8*>(&Bs[rowb * 64 + ((ubase ^ (rowb & 7)) * 8)]);
            }
            #pragma unroll
            for (int fm = 0; fm < 4; ++fm) {
                int rowa = wc * 64 + fm * 16 + l16;
                f16x8 af = *reinterpret_cast<const f16x8*>(&As[rowa * 64 + ((ubase ^ (rowa & 7)) * 8)]);
                #pragma unroll
                for (int fn = 0; fn < 2; ++fn)
                    acc[fm][fn] = __builtin_amdgcn_mfma_f32_16x16x32_f16(af, bfr[fn], acc[fm][fn], 0, 0, 0);
            }
        }
    }

    // per-lane (min1,min2) per fn over fm,r; phantom cells predicated out
    ull m1[2] = {~0ull, ~0ull}, m2[2] = {~0ull, ~0ull};
    #pragma unroll
    for (int fm = 0; fm < 4; ++fm) {
        int cb = c0 + wc * 64 + fm * 16 + g4 * 4;
        float4 wn4 = *reinterpret_cast<const float4*>(&wnorm[cb]);  // ws garbage ok for >=NC (masked)
        float wna[4] = {wn4.x, wn4.y, wn4.z, wn4.w};
        #pragma unroll
        for (int fn = 0; fn < 2; ++fn)
            #pragma unroll
            for (int r = 0; r < 4; ++r) {
                float s = wna[r] - 2.0f * acc[fm][fn][r];
                ull p = (cb + r < NC) ? (((ull)fkey(s) << 32) | (unsigned)(cb + r)) : ~0ull;
                merge2(m1[fn], m2[fn], p, ~0ull);
            }
    }
    #pragma unroll
    for (int fn = 0; fn < 2; ++fn) {
        #pragma unroll
        for (int off = 16; off <= 32; off <<= 1) {
            ull o1 = __shfl_xor(m1[fn], off), o2 = __shfl_xor(m2[fn], off);
            merge2(m1[fn], m2[fn], o1, o2);
        }
    }
    __syncthreads();                   // all MFMA LDS reads done before As reuse
    ull* sm1 = (ull*)&As[0];           // [2][128]
    ull* sm2 = sm1 + 256;
    if (g4 == 0) {
        #pragma unroll
        for (int fn = 0; fn < 2; ++fn) {
            int bl = wb * 32 + fn * 16 + l16;
            sm1[wc * 128 + bl] = m1[fn];
            sm2[wc * 128 + bl] = m2[fn];
        }
    }
    __syncthreads();
    if (tid < 128) {
        ull a1 = sm1[tid], a2 = sm2[tid];
        merge2(a1, a2, sm1[128 + tid], sm2[128 + tid]);
        size_t base = (size_t)(b0 + tid) * PKS + tile * 2;
        pkt[base] = a1;
        pkt[base + 1] = a2;
    }
}

// per-sample: merge ALL 79 tile-pairs (128 threads, 2 waves); gap>=TAU -> BMU certain;
// else exact fp32 over candidate tiles, COALESCED: wave reads one w row per cell
__global__ __launch_bounds__(128) void k_bmu(const ull* __restrict__ pkt, const float* __restrict__ x,
                                             const float* __restrict__ w, int2* __restrict__ bxy) {
    __shared__ ull s1[2], s2[2];
    __shared__ int candList[NT];
    __shared__ int candCnt;
    int b = blockIdx.x;
    int tid = threadIdx.x, lane = tid & 63, wv = tid >> 6;

    ull a1 = ~0ull, a2 = ~0ull;
    if (tid < NT) {
        a1 = pkt[(size_t)b * PKS + tid * 2];
        a2 = pkt[(size_t)b * PKS + tid * 2 + 1];
    }
    #pragma unroll
    for (int off = 1; off <= 32; off <<= 1) {
        ull o1 = __shfl_xor(a1, off), o2 = __shfl_xor(a2, off);
        merge2(a1, a2, o1, o2);
    }
    if (lane == 0) { s1[wv] = a1; s2[wv] = a2; }
    __syncthreads();
    a1 = s1[0]; a2 = s2[0];
    merge2(a1, a2, s1[1], s2[1]);
    float f1 = unfkey((unsigned)(a1 >> 32));
    float f2 = unfkey((unsigned)(a2 >> 32));
    if (f2 - f1 >= TAU) {   // uniform branch
        if (tid == 0) {
            int c = (int)(unsigned)(a1 & 0xffffffffull);
            bxy[b] = make_int2(c / W_, c % W_);
        }
        return;
    }
    // exact path: candidate tiles have tile_min1 <= f1 + TAU
    if (tid == 0) candCnt = 0;
    __syncthreads();
    if (tid < NT) {
        ull mt = pkt[(size_t)b * PKS + tid * 2];
        if (unfkey((unsigned)(mt >> 32)) <= f1 + TAU) {
            int p = atomicAdd(&candCnt, 1);
            candList[p] = tid;
        }
    }
    __syncthreads();
    int n = candCnt;
    float4 xv = *reinterpret_cast<const float4*>(&x[(size_t)b * D_ + lane * 4]);
    ull best = ~0ull;
    for (int ci = 0; ci < n; ++ci) {
        int t = candList[ci];
        for (int i = wv; i < 128; i += 2) {      // 2 waves split the tile's cells
            int c = t * 128 + i;
            if (c < NC) {
                float4 wv4 = *reinterpret_cast<const float4*>(&w[(size_t)c * D_ + lane * 4]);
                float p = wv4.x * (wv4.x - 2.0f * xv.x) + wv4.y * (wv4.y - 2.0f * xv.y)
                        + wv4.z * (wv4.z - 2.0f * xv.z) + wv4.w * (wv4.w - 2.0f * xv.w);
                #pragma unroll
                for (int off = 32; off; off >>= 1) p += __shfl_xor(p, off);
                if (lane == 0) {
                    ull pk = ((ull)fkey(p) << 32) | (unsigned)c;
                    best = pk < best ? pk : best;
                }
            }
        }
    }
    if (lane == 0) s1[wv] = best;
    __syncthreads();
    if (tid == 0) {
        best = s1[0] < s1[1] ? s1[0] : s1[1];
        int c = (int)(unsigned)(best & 0xffffffffull);
        bxy[b] = make_int2(c / W_, c % W_);
    }
}

// chunked 2-pass suffix scan with separable-Gaussian LDS table
__global__ __launch_bounds__(256) void k_scan(const int2* __restrict__ bxy, const int* __restrict__ ep,
                                              const int* __restrict__ tp, ushort_t* __restrict__ coefT,
                                              float* __restrict__ T) {
    __shared__ float E[W_];
    float lr, inv2r2;
    decay_params(ep, tp, lr, inv2r2);
    if (threadIdx.x < W_) {
        float d = (float)threadIdx.x;
        E[threadIdx.x] = __expf(-d * d * inv2r2);
    }
    __syncthreads();

    int g = blockIdx.x * 256 + threadIdx.x;
    int c = g >> 3, t = g & 7;
    if (c >= NC) return;
    int cy = c / W_, cx = c % W_;
    int base = t * 128;

    float P = 1.0f;
    for (int i = base; i < base + 128; ++i) {
        int2 p = bxy[i];
        int dy = abs(p.x - cy), dx = abs(p.y - cx);
        float a = lr * E[dy] * E[dx];
        P *= (1.0f - a);
    }
    int gbase = (threadIdx.x & 63) & ~7;
    float M = 1.0f;
    #pragma unroll
    for (int k = 1; k < 8; ++k) {
        float pk = __shfl(P, gbase + k, 64);
        if (k > t) M *= pk;
    }
    if (t == 0) T[c] = M * P;

    float s = M;
    for (int seg = 15; seg >= 0; --seg) {
        ushort_t buf[8];
        #pragma unroll
        for (int e = 7; e >= 0; --e) {
            int i = base + seg * 8 + e;
            int2 p = bxy[i];
            int dy = abs(p.x - cy), dx = abs(p.y - cx);
            float a = lr * E[dy] * E[dx];
            buf[e] = f2bf(a * s);
            s *= (1.0f - a);
        }
        *reinterpret_cast<uint4*>(&coefT[(size_t)c * B_ + base + seg * 8]) =
            *reinterpret_cast<uint4*>(buf);
    }
}

// update GEMM via bf16 MFMA, SINGLE-buffer gl_lds staging (R5-proven), XCD-swizzled grid
__global__ __launch_bounds__(256) void k_update(const ushort_t* __restrict__ coefT, const ushort_t* __restrict__ xhT,
                                                const float* __restrict__ T, const float* __restrict__ w0,
                                                float* __restrict__ out) {
    __shared__ __align__(16) ushort_t As[64 * 64];
    __shared__ __align__(16) ushort_t Bs[64 * 64];
    const int tid = threadIdx.x;
    int orig = blockIdx.y * gridDim.x + blockIdx.x;
    int wgid = xcd_swz(orig, 4 * 157);
    const int d0 = (wgid & 3) * 64;
    const int c0 = (wgid >> 2) * 64;
    const int wid = tid >> 6, lane = tid & 63;
    const int wc = wid >> 1, wd = wid & 1;
    const int g4 = lane >> 4, l16 = lane & 15;

    f32x4 acc[2][2] = {};

    for (int k0 = 0; k0 < B_; k0 += 64) {
        if (k0) __syncthreads();
        #pragma unroll
        for (int r = 0; r < 2; ++r) {
            int f = tid + r * 256;        // [0,512): 64 rows x 8 16B-units
            int row = f >> 3, u = f & 7;
            int ug = (u ^ (row & 7)) * 8;
            int cc = c0 + row; if (cc > NC - 1) cc = NC - 1;
            gl_lds16(&coefT[(size_t)cc * B_ + k0 + ug], &As[(f & ~63) * 8]);
            gl_lds16(&xhT[(size_t)(d0 + row) * B_ + k0 + ug], &Bs[(f & ~63) * 8]);
        }
        __syncthreads();
        #pragma unroll
        for (int kh = 0; kh < 2; ++kh) {
            bf16x8 af[2], bfr[2];
            int ubase = kh * 4 + g4;
            #pragma unroll
            for (int fm = 0; fm < 2; ++fm) {
                int rowa = wc * 32 + fm * 16 + l16;
                af[fm] = *reinterpret_cast<const bf16x8*>(&As[rowa * 64 + ((ubase ^ (rowa & 7)) * 8)]);
                int rowb = wd * 32 + fm * 16 + l16;
                bfr[fm] = *reinterpret_cast<const bf16x8*>(&Bs[rowb * 64 + ((ubase ^ (rowb & 7)) * 8)]);
            }
            #pragma unroll
            for (int fm = 0; fm < 2; ++fm)
                #pragma unroll
                for (int fn = 0; fn < 2; ++fn)
                    acc[fm][fn] = __builtin_amdgcn_mfma_f32_16x16x32_bf16(af[fm], bfr[fn], acc[fm][fn], 0, 0, 0);
        }
    }

    #pragma unroll
    for (int fm = 0; fm < 2; ++fm) {
        #pragma unroll
        for (int r = 0; r < 4; ++r) {
            int c = c0 + wc * 32 + fm * 16 + g4 * 4 + r;
            if (c < NC) {
                float t = T[c];
                #pragma unroll
                for (int fn = 0; fn < 2; ++fn) {
                    int d = d0 + wd * 32 + fn * 16 + l16;
                    out[(size_t)c * D_ + d] = fmaf(t, w0[(size_t)c * D_ + d], acc[fm][fn][r]);
                }
            }
        }
    }
}

// ---------- tiny-ws fallback path ----------
__global__ void k_initfix(ull* packed_fix) {
    int i = blockIdx.x * 256 + threadIdx.x;
    if (i < B_) packed_fix[i] = ~0ull;
}
__global__ __launch_bounds__(256) void k_exact_bmu(const float* __restrict__ x, const float* __restrict__ w,
                                                   ull* __restrict__ packed_fix) {
    int b = blockIdx.x;
    int wid = threadIdx.x >> 6, lane = threadIdx.x & 63;
    float4 xv = *reinterpret_cast<const float4*>(&x[(size_t)b * D_ + lane * 4]);
    ull best = ~0ull;
    for (int c = wid; c < NC; c += 4) {
        float4 wv = *reinterpret_cast<const float4*>(&w[(size_t)c * D_ + lane * 4]);
        float p = wv.x * (wv.x - 2.0f * xv.x) + wv.y * (wv.y - 2.0f * xv.y)
                + wv.z * (wv.z - 2.0f * xv.z) + wv.w * (wv.w - 2.0f * xv.w);
        #pragma unroll
        for (int off = 32; off; off >>= 1) p += __shfl_xor(p, off);
        if (lane == 0) {
            ull pk = ((ull)fkey(p) << 32) | (unsigned)c;
            best = pk < best ? pk : best;
        }
    }
    if (lane == 0) atomicMin(&packed_fix[b], best);
}
__global__ void k_decode_force(const ull* __restrict__ packed_fix, float2* __restrict__ xy) {
    int i = blockIdx.x * 256 + threadIdx.x;
    if (i < B_) {
        int c = (int)(unsigned)(packed_fix[i] & 0xffffffffull);
        xy[i] = make_float2((float)(c / W_), (float)(c % W_));
    }
}
__global__ __launch_bounds__(256) void k_update_fallback(const float* __restrict__ x, const float* __restrict__ w0,
                                                         const float2* __restrict__ xy, const int* ep, const int* tp,
                                                         float* __restrict__ out) {
    int c = blockIdx.x;
    int d = threadIdx.x;
    float cyf = (float)(c / W_), cxf = (float)(c % W_);
    float lr, inv2r2;
    decay_params(ep, tp, lr, inv2r2);
    float acc = w0[(size_t)c * D_ + d];
    for (int i = 0; i < B_; ++i) {
        float2 p = xy[i];
        float dy = p.x - cyf, dx = p.y - cxf;
        float a = lr * __expf(-(dy * dy + dx * dx) * inv2r2);
        acc = fmaf(a, x[(size_t)i * D_ + d] - acc, acc);
    }
    out[(size_t)c * D_ + d] = acc;
}

extern "C" void kernel_launch(void* const* d_in, const int* in_sizes, int n_in,
                              void* d_out, int out_size, void* d_ws, size_t ws_size,
                              hipStream_t stream) {
    const float* x = (const float*)d_in[0];
    const float* w = (const float*)d_in[1];
    const int* ep = (const int*)d_in[2];
    const int* tp = (const int*)d_in[3];
    float* out = (float*)d_out;

    char* ws = (char*)d_ws;
    ull* packed_fix = (ull*)(ws + 8192);             // 8KB    @ 8K (fallback only)
    int2* bxy       = (int2*)(ws + 16384);           // 8KB    @ 16K
    float2* xyf     = (float2*)(ws + 16384);         // (fallback alias)
    float* T        = (float*)(ws + 24576);          // 40KB   @ 24K
    float* wnorm    = (float*)(ws + 65536);          // 40.5KB @ 64K
    ushort_t* xhT   = (ushort_t*)(ws + 131072);      // 512KB  @ 128K
    __half* xh      = (__half*)(ws + 655360);        // 512KB
    __half* wh      = (__half*)(ws + 1179648);       // 5.12MB
    ushort_t* coefT = (ushort_t*)(ws + 6553600);     // 20.48MB
    ull* pkt        = (ull*)(ws + 27262976);         // 1024*160*8 = 1.31MB
    size_t required = 27262976 + (size_t)B_ * PKS * 8;  // ~28.6MB

    if (ws_size >= required) {
        k_prep<<<NC / 4 + 64, 256, 0, stream>>>(w, x, wh, wnorm, xh, xhT);
        k_scores_mfma<<<dim3(8, NT), 512, 0, stream>>>(wh, xh, wnorm, pkt);
        k_bmu<<<B_, 128, 0, stream>>>(pkt, x, w, bxy);
        k_scan<<<(NC * 8 + 255) / 256, 256, 0, stream>>>(bxy, ep, tp, coefT, T);
        k_update<<<dim3(4, 157), 256, 0, stream>>>(coefT, xhT, T, w, out);
    } else {
        k_initfix<<<4, 256, 0, stream>>>(packed_fix);
        k_exact_bmu<<<B_, 256, 0, stream>>>(x, w, packed_fix);
        k_decode_force<<<4, 256, 0, stream>>>(packed_fix, xyf);
        k_update_fallback<<<NC, 256, 0, stream>>>(x, w, xyf, ep, tp, out);
    }
}

// Round 9
// 146.178 us; speedup vs baseline: 1.3793x; 1.3793x over previous
//
#include <hip/hip_runtime.h>
#include <hip/hip_fp16.h>

typedef unsigned long long ull;
typedef unsigned short ushort_t;
typedef unsigned int u32;
typedef short bf16x8 __attribute__((ext_vector_type(8)));
typedef _Float16 f16x8 __attribute__((ext_vector_type(8)));
typedef float f32x4 __attribute__((ext_vector_type(4)));

#define NC 10000   // H*W cells
#define D_ 256     // input dim
#define B_ 1024    // batch
#define W_ 100     // grid width
#define NT 79      // score c-tiles (128 cells each)
#define PKS 160    // pkt row stride in ull
#define TAU 0.10f  // >= 2*eps_score for fp16-input MFMA scores (proven R7)

// async global->LDS, 16B per lane; LDS dest = wave-uniform base + lane*16
__device__ __forceinline__ void gl_lds16(const void* g, void* l) {
    __builtin_amdgcn_global_load_lds(
        (const __attribute__((address_space(1))) u32*)g,
        (__attribute__((address_space(3))) u32*)l,
        16, 0, 0);
}

// bijective XCD-chunk swizzle (m204)
__device__ __forceinline__ int xcd_swz(int orig, int nwg) {
    int q = nwg >> 3, r = nwg & 7;
    int xcd = orig & 7, off = orig >> 3;
    return (xcd < r ? xcd * (q + 1) : r * (q + 1) + (xcd - r) * q) + off;
}

// monotonic float -> sortable uint mapping
__device__ __forceinline__ unsigned fkey(float f) {
    unsigned u = __float_as_uint(f);
    return (u & 0x80000000u) ? ~u : (u | 0x80000000u);
}
__device__ __forceinline__ float unfkey(unsigned k) {
    unsigned u = (k & 0x80000000u) ? (k ^ 0x80000000u) : ~k;
    return __uint_as_float(u);
}

// exact RNE float -> bf16 bits
__device__ __forceinline__ ushort_t f2bf(float f) {
    unsigned u = __float_as_uint(f);
    unsigned r = (u + 0x7fffu + ((u >> 16) & 1u)) >> 16;
    return (ushort_t)r;
}

__device__ __forceinline__ void decay_params(const int* ep, const int* tp, float& lr, float& inv2r2) {
    double decay = 1.0 - (double)(*ep) / (double)(*tp);
    lr = (float)(0.5 * decay);
    float radius = (float)(50.0 * decay);
    inv2r2 = 1.0f / (2.0f * radius * radius);
}

// sorted-pair merge: (a1,a2) <- two smallest of {a1,a2,c1,c2}  (a1<=a2, c1<=c2)
__device__ __forceinline__ void merge2(ull& a1, ull& a2, ull c1, ull c2) {
    ull m1 = a1 < c1 ? a1 : c1;
    ull hi = a1 < c1 ? c1 : a1;
    ull lo2 = a2 < c2 ? a2 : c2;
    a2 = hi < lo2 ? hi : lo2;
    a1 = m1;
}

// fused prep: blocks [0,2500) = w -> wh fp16 + wnorm; blocks [2500,2564) = x -> xh fp16 + xhT bf16
__global__ __launch_bounds__(256) void k_prep(const float* __restrict__ w, const float* __restrict__ x,
                                              __half* __restrict__ wh, float* __restrict__ wnorm,
                                              __half* __restrict__ xh, ushort_t* __restrict__ xhT) {
    int bid = blockIdx.x;
    int tid = threadIdx.x;
    if (bid < NC / 4) {
        int cell = bid * 4 + (tid >> 6);
        int lane = tid & 63;
        float4 v = *reinterpret_cast<const float4*>(&w[(size_t)cell * D_ + lane * 4]);
        float s = v.x * v.x + v.y * v.y + v.z * v.z + v.w * v.w;
        __half hb[4];
        float e[4] = {v.x, v.y, v.z, v.w};
        #pragma unroll
        for (int i = 0; i < 4; ++i) hb[i] = __float2half(e[i]);
        *reinterpret_cast<uint2*>(&wh[(size_t)cell * D_ + lane * 4]) = *reinterpret_cast<uint2*>(hb);
        #pragma unroll
        for (int off = 32; off; off >>= 1) s += __shfl_xor(s, off);
        if (lane == 0) wnorm[cell] = s;
    } else {
        __shared__ ushort_t tile[64][65];
        int idx = bid - NC / 4;
        int b0 = (idx & 15) * 64, d0 = (idx >> 4) * 64;
        #pragma unroll
        for (int r = 0; r < 16; ++r) {
            int f = r * 256 + tid;
            int i = f >> 6, j = f & 63;       // i = b-local, j = d-local
            float v = x[(size_t)(b0 + i) * D_ + d0 + j];
            xh[(size_t)(b0 + i) * D_ + d0 + j] = __float2half(v);
            tile[j][i] = f2bf(v);
        }
        __syncthreads();
        #pragma unroll
        for (int r = 0; r < 2; ++r) {
            int f = r * 256 + tid;            // [0,512): 64 d-rows x 8 units
            int row = f >> 3, u = f & 7;
            ushort_t v[8];
            #pragma unroll
            for (int e = 0; e < 8; ++e) v[e] = tile[row][u * 8 + e];
            *reinterpret_cast<uint4*>(&xhT[(size_t)(d0 + row) * B_ + b0 + u * 8]) =
                *reinterpret_cast<uint4*>(v);
        }
    }
}

// fp16 scores GEMM with fused per-tile (min1,min2) epilogue -> pkt[b][tile]
// tile 128 cells x 128 batch, BK=64, 8 waves (2 cell x 4 batch), single-buffer staging
__global__ __launch_bounds__(512) void k_scores_mfma(const __half* __restrict__ wh, const __half* __restrict__ xh,
                                                     const float* __restrict__ wnorm, ull* __restrict__ pkt) {
    __shared__ __align__(16) __half As[128 * 64];  // cells x k  (16KB)
    __shared__ __align__(16) __half Bs[128 * 64];  // batch x k  (16KB)
    const int tid = threadIdx.x;
    int orig = blockIdx.y * gridDim.x + blockIdx.x;
    int wgid = xcd_swz(orig, 8 * NT);
    const int b0 = (wgid & 7) * 128;
    const int c0 = (wgid >> 3) * 128;
    const int tile = wgid >> 3;
    const int wid = tid >> 6, lane = tid & 63;
    const int wc = wid >> 2;           // 0..1 -> 64 cells
    const int wb = wid & 3;            // 0..3 -> 32 batch
    const int g4 = lane >> 4, l16 = lane & 15;

    f32x4 acc[4][2] = {};

    for (int k0 = 0; k0 < D_; k0 += 64) {
        if (k0) __syncthreads();
        #pragma unroll
        for (int r = 0; r < 2; ++r) {
            int f = tid + r * 512;        // [0,1024): 128 rows x 8 16B-units
            int row = f >> 3, u = f & 7;
            int ug = (u ^ (row & 7)) * 8;
            int cc = c0 + row; if (cc > NC - 1) cc = NC - 1;
            gl_lds16(&wh[(size_t)cc * D_ + k0 + ug], &As[(f & ~63) * 8]);
            gl_lds16(&xh[(size_t)(b0 + row) * D_ + k0 + ug], &Bs[(f & ~63) * 8]);
        }
        __syncthreads();
        #pragma unroll
        for (int kh = 0; kh < 2; ++kh) {
            int ubase = kh * 4 + g4;
            f16x8 bfr[2];
            #pragma unroll
            for (int fn = 0; fn < 2; ++fn) {
                int rowb = wb * 32 + fn * 16 + l16;
                bfr[fn] = *reinterpret_cast<const f16x8*>(&Bs[rowb * 64 + ((ubase ^ (rowb & 7)) * 8)]);
            }
            #pragma unroll
            for (int fm = 0; fm < 4; ++fm) {
                int rowa = wc * 64 + fm * 16 + l16;
                f16x8 af = *reinterpret_cast<const f16x8*>(&As[rowa * 64 + ((ubase ^ (rowa & 7)) * 8)]);
                #pragma unroll
                for (int fn = 0; fn < 2; ++fn)
                    acc[fm][fn] = __builtin_amdgcn_mfma_f32_16x16x32_f16(af, bfr[fn], acc[fm][fn], 0, 0, 0);
            }
        }
    }

    // per-lane (min1,min2) per fn over fm,r; phantom cells predicated out
    ull m1[2] = {~0ull, ~0ull}, m2[2] = {~0ull, ~0ull};
    #pragma unroll
    for (int fm = 0; fm < 4; ++fm) {
        int cb = c0 + wc * 64 + fm * 16 + g4 * 4;
        float4 wn4 = *reinterpret_cast<const float4*>(&wnorm[cb]);  // ws garbage ok for >=NC (masked)
        float wna[4] = {wn4.x, wn4.y, wn4.z, wn4.w};
        #pragma unroll
        for (int fn = 0; fn < 2; ++fn)
            #pragma unroll
            for (int r = 0; r < 4; ++r) {
                float s = wna[r] - 2.0f * acc[fm][fn][r];
                ull p = (cb + r < NC) ? (((ull)fkey(s) << 32) | (unsigned)(cb + r)) : ~0ull;
                merge2(m1[fn], m2[fn], p, ~0ull);
            }
    }
    #pragma unroll
    for (int fn = 0; fn < 2; ++fn) {
        #pragma unroll
        for (int off = 16; off <= 32; off <<= 1) {
            ull o1 = __shfl_xor(m1[fn], off), o2 = __shfl_xor(m2[fn], off);
            merge2(m1[fn], m2[fn], o1, o2);
        }
    }
    __syncthreads();                   // all MFMA LDS reads done before As reuse
    ull* sm1 = (ull*)&As[0];           // [2][128]
    ull* sm2 = sm1 + 256;
    if (g4 == 0) {
        #pragma unroll
        for (int fn = 0; fn < 2; ++fn) {
            int bl = wb * 32 + fn * 16 + l16;
            sm1[wc * 128 + bl] = m1[fn];
            sm2[wc * 128 + bl] = m2[fn];
        }
    }
    __syncthreads();
    if (tid < 128) {
        ull a1 = sm1[tid], a2 = sm2[tid];
        merge2(a1, a2, sm1[128 + tid], sm2[128 + tid]);
        size_t base = (size_t)(b0 + tid) * PKS + tile * 2;
        pkt[base] = a1;
        pkt[base + 1] = a2;
    }
}

// per-sample: merge ALL 79 tile-pairs (256 threads, 4 waves); gap>=TAU -> BMU certain;
// else exact fp32 over candidate tiles: wave-per-cell (one float4/lane = full row),
// 4 waves parallel + unroll-4 for pipelined independent load+reduce streams
__global__ __launch_bounds__(256) void k_bmu(const ull* __restrict__ pkt, const float* __restrict__ x,
                                             const float* __restrict__ w, int2* __restrict__ bxy) {
    __shared__ ull s1[4], s2[4];
    __shared__ int candList[NT];
    __shared__ int candCnt;
    int b = blockIdx.x;
    int tid = threadIdx.x, lane = tid & 63, wv = tid >> 6;

    ull a1 = ~0ull, a2 = ~0ull;
    if (tid < NT) {
        a1 = pkt[(size_t)b * PKS + tid * 2];
        a2 = pkt[(size_t)b * PKS + tid * 2 + 1];
    }
    #pragma unroll
    for (int off = 1; off <= 32; off <<= 1) {
        ull o1 = __shfl_xor(a1, off), o2 = __shfl_xor(a2, off);
        merge2(a1, a2, o1, o2);
    }
    if (lane == 0) { s1[wv] = a1; s2[wv] = a2; }
    __syncthreads();
    a1 = s1[0]; a2 = s2[0];
    #pragma unroll
    for (int k = 1; k < 4; ++k) merge2(a1, a2, s1[k], s2[k]);
    float f1 = unfkey((unsigned)(a1 >> 32));
    float f2 = unfkey((unsigned)(a2 >> 32));
    if (f2 - f1 >= TAU) {   // uniform branch: identical f1,f2 across block
        if (tid == 0) {
            int c = (int)(unsigned)(a1 & 0xffffffffull);
            bxy[b] = make_int2(c / W_, c % W_);
        }
        return;
    }
    // exact path: candidate tiles have tile_min1 <= f1 + TAU (order-independent min -> deterministic)
    if (tid == 0) candCnt = 0;
    __syncthreads();
    if (tid < NT) {
        ull mt = pkt[(size_t)b * PKS + tid * 2];
        if (unfkey((unsigned)(mt >> 32)) <= f1 + TAU) {
            int p = atomicAdd(&candCnt, 1);
            candList[p] = tid;
        }
    }
    __syncthreads();
    int n = candCnt;
    float4 xv = *reinterpret_cast<const float4*>(&x[(size_t)b * D_ + lane * 4]);
    ull best = ~0ull;
    for (int ci = 0; ci < n; ++ci) {
        int t = candList[ci];
        #pragma unroll 4
        for (int i = wv; i < 128; i += 4) {      // 4 waves x unroll-4: 16 streams in flight
            int c = t * 128 + i;                 // wave-uniform
            if (c < NC) {
                float4 wv4 = *reinterpret_cast<const float4*>(&w[(size_t)c * D_ + lane * 4]);
                float p = wv4.x * (wv4.x - 2.0f * xv.x) + wv4.y * (wv4.y - 2.0f * xv.y)
                        + wv4.z * (wv4.z - 2.0f * xv.z) + wv4.w * (wv4.w - 2.0f * xv.w);
                #pragma unroll
                for (int off = 32; off; off >>= 1) p += __shfl_xor(p, off);
                if (lane == 0) {
                    ull pk = ((ull)fkey(p) << 32) | (unsigned)c;
                    best = pk < best ? pk : best;
                }
            }
        }
    }
    if (lane == 0) s1[wv] = best;
    __syncthreads();
    if (tid == 0) {
        best = s1[0];
        #pragma unroll
        for (int k = 1; k < 4; ++k) best = s1[k] < best ? s1[k] : best;
        int c = (int)(unsigned)(best & 0xffffffffull);
        bxy[b] = make_int2(c / W_, c % W_);
    }
}

// chunked 2-pass suffix scan with separable-Gaussian LDS table
__global__ __launch_bounds__(256) void k_scan(const int2* __restrict__ bxy, const int* __restrict__ ep,
                                              const int* __restrict__ tp, ushort_t* __restrict__ coefT,
                                              float* __restrict__ T) {
    __shared__ float E[W_];
    float lr, inv2r2;
    decay_params(ep, tp, lr, inv2r2);
    if (threadIdx.x < W_) {
        float d = (float)threadIdx.x;
        E[threadIdx.x] = __expf(-d * d * inv2r2);
    }
    __syncthreads();

    int g = blockIdx.x * 256 + threadIdx.x;
    int c = g >> 3, t = g & 7;
    if (c >= NC) return;
    int cy = c / W_, cx = c % W_;
    int base = t * 128;

    float P = 1.0f;
    for (int i = base; i < base + 128; ++i) {
        int2 p = bxy[i];
        int dy = abs(p.x - cy), dx = abs(p.y - cx);
        float a = lr * E[dy] * E[dx];
        P *= (1.0f - a);
    }
    int gbase = (threadIdx.x & 63) & ~7;
    float M = 1.0f;
    #pragma unroll
    for (int k = 1; k < 8; ++k) {
        float pk = __shfl(P, gbase + k, 64);
        if (k > t) M *= pk;
    }
    if (t == 0) T[c] = M * P;

    float s = M;
    for (int seg = 15; seg >= 0; --seg) {
        ushort_t buf[8];
        #pragma unroll
        for (int e = 7; e >= 0; --e) {
            int i = base + seg * 8 + e;
            int2 p = bxy[i];
            int dy = abs(p.x - cy), dx = abs(p.y - cx);
            float a = lr * E[dy] * E[dx];
            buf[e] = f2bf(a * s);
            s *= (1.0f - a);
        }
        *reinterpret_cast<uint4*>(&coefT[(size_t)c * B_ + base + seg * 8]) =
            *reinterpret_cast<uint4*>(buf);
    }
}

// update GEMM via bf16 MFMA, single-buffer gl_lds staging, XCD-swizzled grid
__global__ __launch_bounds__(256) void k_update(const ushort_t* __restrict__ coefT, const ushort_t* __restrict__ xhT,
                                                const float* __restrict__ T, const float* __restrict__ w0,
                                                float* __restrict__ out) {
    __shared__ __align__(16) ushort_t As[64 * 64];
    __shared__ __align__(16) ushort_t Bs[64 * 64];
    const int tid = threadIdx.x;
    int orig = blockIdx.y * gridDim.x + blockIdx.x;
    int wgid = xcd_swz(orig, 4 * 157);
    const int d0 = (wgid & 3) * 64;
    const int c0 = (wgid >> 2) * 64;
    const int wid = tid >> 6, lane = tid & 63;
    const int wc = wid >> 1, wd = wid & 1;
    const int g4 = lane >> 4, l16 = lane & 15;

    f32x4 acc[2][2] = {};

    for (int k0 = 0; k0 < B_; k0 += 64) {
        if (k0) __syncthreads();
        #pragma unroll
        for (int r = 0; r < 2; ++r) {
            int f = tid + r * 256;        // [0,512): 64 rows x 8 16B-units
            int row = f >> 3, u = f & 7;
            int ug = (u ^ (row & 7)) * 8;
            int cc = c0 + row; if (cc > NC - 1) cc = NC - 1;
            gl_lds16(&coefT[(size_t)cc * B_ + k0 + ug], &As[(f & ~63) * 8]);
            gl_lds16(&xhT[(size_t)(d0 + row) * B_ + k0 + ug], &Bs[(f & ~63) * 8]);
        }
        __syncthreads();
        #pragma unroll
        for (int kh = 0; kh < 2; ++kh) {
            bf16x8 af[2], bfr[2];
            int ubase = kh * 4 + g4;
            #pragma unroll
            for (int fm = 0; fm < 2; ++fm) {
                int rowa = wc * 32 + fm * 16 + l16;
                af[fm] = *reinterpret_cast<const bf16x8*>(&As[rowa * 64 + ((ubase ^ (rowa & 7)) * 8)]);
                int rowb = wd * 32 + fm * 16 + l16;
                bfr[fm] = *reinterpret_cast<const bf16x8*>(&Bs[rowb * 64 + ((ubase ^ (rowb & 7)) * 8)]);
            }
            #pragma unroll
            for (int fm = 0; fm < 2; ++fm)
                #pragma unroll
                for (int fn = 0; fn < 2; ++fn)
                    acc[fm][fn] = __builtin_amdgcn_mfma_f32_16x16x32_bf16(af[fm], bfr[fn], acc[fm][fn], 0, 0, 0);
        }
    }

    #pragma unroll
    for (int fm = 0; fm < 2; ++fm) {
        #pragma unroll
        for (int r = 0; r < 4; ++r) {
            int c = c0 + wc * 32 + fm * 16 + g4 * 4 + r;
            if (c < NC) {
                float t = T[c];
                #pragma unroll
                for (int fn = 0; fn < 2; ++fn) {
                    int d = d0 + wd * 32 + fn * 16 + l16;
                    out[(size_t)c * D_ + d] = fmaf(t, w0[(size_t)c * D_ + d], acc[fm][fn][r]);
                }
            }
        }
    }
}

// ---------- tiny-ws fallback path ----------
__global__ void k_initfix(ull* packed_fix) {
    int i = blockIdx.x * 256 + threadIdx.x;
    if (i < B_) packed_fix[i] = ~0ull;
}
__global__ __launch_bounds__(256) void k_exact_bmu(const float* __restrict__ x, const float* __restrict__ w,
                                                   ull* __restrict__ packed_fix) {
    int b = blockIdx.x;
    int wid = threadIdx.x >> 6, lane = threadIdx.x & 63;
    float4 xv = *reinterpret_cast<const float4*>(&x[(size_t)b * D_ + lane * 4]);
    ull best = ~0ull;
    for (int c = wid; c < NC; c += 4) {
        float4 wv = *reinterpret_cast<const float4*>(&w[(size_t)c * D_ + lane * 4]);
        float p = wv.x * (wv.x - 2.0f * xv.x) + wv.y * (wv.y - 2.0f * xv.y)
                + wv.z * (wv.z - 2.0f * xv.z) + wv.w * (wv.w - 2.0f * xv.w);
        #pragma unroll
        for (int off = 32; off; off >>= 1) p += __shfl_xor(p, off);
        if (lane == 0) {
            ull pk = ((ull)fkey(p) << 32) | (unsigned)c;
            best = pk < best ? pk : best;
        }
    }
    if (lane == 0) atomicMin(&packed_fix[b], best);
}
__global__ void k_decode_force(const ull* __restrict__ packed_fix, float2* __restrict__ xy) {
    int i = blockIdx.x * 256 + threadIdx.x;
    if (i < B_) {
        int c = (int)(unsigned)(packed_fix[i] & 0xffffffffull);
        xy[i] = make_float2((float)(c / W_), (float)(c % W_));
    }
}
__global__ __launch_bounds__(256) void k_update_fallback(const float* __restrict__ x, const float* __restrict__ w0,
                                                         const float2* __restrict__ xy, const int* ep, const int* tp,
                                                         float* __restrict__ out) {
    int c = blockIdx.x;
    int d = threadIdx.x;
    float cyf = (float)(c / W_), cxf = (float)(c % W_);
    float lr, inv2r2;
    decay_params(ep, tp, lr, inv2r2);
    float acc = w0[(size_t)c * D_ + d];
    for (int i = 0; i < B_; ++i) {
        float2 p = xy[i];
        float dy = p.x - cyf, dx = p.y - cxf;
        float a = lr * __expf(-(dy * dy + dx * dx) * inv2r2);
        acc = fmaf(a, x[(size_t)i * D_ + d] - acc, acc);
    }
    out[(size_t)c * D_ + d] = acc;
}

extern "C" void kernel_launch(void* const* d_in, const int* in_sizes, int n_in,
                              void* d_out, int out_size, void* d_ws, size_t ws_size,
                              hipStream_t stream) {
    const float* x = (const float*)d_in[0];
    const float* w = (const float*)d_in[1];
    const int* ep = (const int*)d_in[2];
    const int* tp = (const int*)d_in[3];
    float* out = (float*)d_out;

    char* ws = (char*)d_ws;
    ull* packed_fix = (ull*)(ws + 8192);             // 8KB    @ 8K (fallback only)
    int2* bxy       = (int2*)(ws + 16384);           // 8KB    @ 16K
    float2* xyf     = (float2*)(ws + 16384);         // (fallback alias)
    float* T        = (float*)(ws + 24576);          // 40KB   @ 24K
    float* wnorm    = (float*)(ws + 65536);          // 40.5KB @ 64K
    ushort_t* xhT   = (ushort_t*)(ws + 131072);      // 512KB  @ 128K
    __half* xh      = (__half*)(ws + 655360);        // 512KB
    __half* wh      = (__half*)(ws + 1179648);       // 5.12MB
    ushort_t* coefT = (ushort_t*)(ws + 6553600);     // 20.48MB
    ull* pkt        = (ull*)(ws + 27262976);         // 1024*160*8 = 1.31MB
    size_t required = 27262976 + (size_t)B_ * PKS * 8;  // ~28.6MB

    if (ws_size >= required) {
        k_prep<<<NC / 4 + 64, 256, 0, stream>>>(w, x, wh, wnorm, xh, xhT);
        k_scores_mfma<<<dim3(8, NT), 512, 0, stream>>>(wh, xh, wnorm, pkt);
        k_bmu<<<B_, 256, 0, stream>>>(pkt, x, w, bxy);
        k_scan<<<(NC * 8 + 255) / 256, 256, 0, stream>>>(bxy, ep, tp, coefT, T);
        k_update<<<dim3(4, 157), 256, 0, stream>>>(coefT, xhT, T, w, out);
    } else {
        k_initfix<<<4, 256, 0, stream>>>(packed_fix);
        k_exact_bmu<<<B_, 256, 0, stream>>>(x, w, packed_fix);
        k_decode_force<<<4, 256, 0, stream>>>(packed_fix, xyf);
        k_update_fallback<<<NC, 256, 0, stream>>>(x, w, xyf, ep, tp, out);
    }
}

// Round 10
// 112.308 us; speedup vs baseline: 1.7953x; 1.3016x over previous
//
#include <hip/hip_runtime.h>
#include <hip/hip_fp16.h>

typedef unsigned long long ull;
typedef unsigned short ushort_t;
typedef unsigned int u32;
typedef short bf16x8 __attribute__((ext_vector_type(8)));
typedef _Float16 f16x8 __attribute__((ext_vector_type(8)));
typedef float f32x4 __attribute__((ext_vector_type(4)));

#define NC 10000   // H*W cells
#define D_ 256     // input dim
#define B_ 1024    // batch
#define W_ 100     // grid width
#define NT 79      // score c-tiles (128 cells each)
#define PKS 160    // pkt row stride in ull
#define TAU 0.10f  // >= 2*eps_score for fp16-input MFMA scores (proven R7/R9)
#define MAXC 16    // parallel exact-path blocks per sample (wraps if candN>16)

// async global->LDS, 16B per lane; LDS dest = wave-uniform base + lane*16
__device__ __forceinline__ void gl_lds16(const void* g, void* l) {
    __builtin_amdgcn_global_load_lds(
        (const __attribute__((address_space(1))) u32*)g,
        (__attribute__((address_space(3))) u32*)l,
        16, 0, 0);
}

// bijective XCD-chunk swizzle (m204)
__device__ __forceinline__ int xcd_swz(int orig, int nwg) {
    int q = nwg >> 3, r = nwg & 7;
    int xcd = orig & 7, off = orig >> 3;
    return (xcd < r ? xcd * (q + 1) : r * (q + 1) + (xcd - r) * q) + off;
}

// monotonic float -> sortable uint mapping
__device__ __forceinline__ unsigned fkey(float f) {
    unsigned u = __float_as_uint(f);
    return (u & 0x80000000u) ? ~u : (u | 0x80000000u);
}
__device__ __forceinline__ float unfkey(unsigned k) {
    unsigned u = (k & 0x80000000u) ? (k ^ 0x80000000u) : ~k;
    return __uint_as_float(u);
}

// exact RNE float -> bf16 bits
__device__ __forceinline__ ushort_t f2bf(float f) {
    unsigned u = __float_as_uint(f);
    unsigned r = (u + 0x7fffu + ((u >> 16) & 1u)) >> 16;
    return (ushort_t)r;
}

__device__ __forceinline__ void decay_params(const int* ep, const int* tp, float& lr, float& inv2r2) {
    double decay = 1.0 - (double)(*ep) / (double)(*tp);
    lr = (float)(0.5 * decay);
    float radius = (float)(50.0 * decay);
    inv2r2 = 1.0f / (2.0f * radius * radius);
}

// sorted-pair merge: (a1,a2) <- two smallest of {a1,a2,c1,c2}  (a1<=a2, c1<=c2)
__device__ __forceinline__ void merge2(ull& a1, ull& a2, ull c1, ull c2) {
    ull m1 = a1 < c1 ? a1 : c1;
    ull hi = a1 < c1 ? c1 : a1;
    ull lo2 = a2 < c2 ? a2 : c2;
    a2 = hi < lo2 ? hi : lo2;
    a1 = m1;
}

// fused prep: blocks [0,2500) = w -> wh fp16 + wnorm; blocks [2500,2564) = x -> xh fp16 + xhT bf16
__global__ __launch_bounds__(256) void k_prep(const float* __restrict__ w, const float* __restrict__ x,
                                              __half* __restrict__ wh, float* __restrict__ wnorm,
                                              __half* __restrict__ xh, ushort_t* __restrict__ xhT) {
    int bid = blockIdx.x;
    int tid = threadIdx.x;
    if (bid < NC / 4) {
        int cell = bid * 4 + (tid >> 6);
        int lane = tid & 63;
        float4 v = *reinterpret_cast<const float4*>(&w[(size_t)cell * D_ + lane * 4]);
        float s = v.x * v.x + v.y * v.y + v.z * v.z + v.w * v.w;
        __half hb[4];
        float e[4] = {v.x, v.y, v.z, v.w};
        #pragma unroll
        for (int i = 0; i < 4; ++i) hb[i] = __float2half(e[i]);
        *reinterpret_cast<uint2*>(&wh[(size_t)cell * D_ + lane * 4]) = *reinterpret_cast<uint2*>(hb);
        #pragma unroll
        for (int off = 32; off; off >>= 1) s += __shfl_xor(s, off);
        if (lane == 0) wnorm[cell] = s;
    } else {
        __shared__ ushort_t tile[64][65];
        int idx = bid - NC / 4;
        int b0 = (idx & 15) * 64, d0 = (idx >> 4) * 64;
        #pragma unroll
        for (int r = 0; r < 16; ++r) {
            int f = r * 256 + tid;
            int i = f >> 6, j = f & 63;       // i = b-local, j = d-local
            float v = x[(size_t)(b0 + i) * D_ + d0 + j];
            xh[(size_t)(b0 + i) * D_ + d0 + j] = __float2half(v);
            tile[j][i] = f2bf(v);
        }
        __syncthreads();
        #pragma unroll
        for (int r = 0; r < 2; ++r) {
            int f = r * 256 + tid;            // [0,512): 64 d-rows x 8 units
            int row = f >> 3, u = f & 7;
            ushort_t v[8];
            #pragma unroll
            for (int e = 0; e < 8; ++e) v[e] = tile[row][u * 8 + e];
            *reinterpret_cast<uint4*>(&xhT[(size_t)(d0 + row) * B_ + b0 + u * 8]) =
                *reinterpret_cast<uint4*>(v);
        }
    }
}

// fp16 scores GEMM with fused per-tile (min1,min2) epilogue -> pkt[b][tile]
// tile 128 cells x 128 batch, BK=64, 8 waves (2 cell x 4 batch), single-buffer staging
__global__ __launch_bounds__(512) void k_scores_mfma(const __half* __restrict__ wh, const __half* __restrict__ xh,
                                                     const float* __restrict__ wnorm, ull* __restrict__ pkt) {
    __shared__ __align__(16) __half As[128 * 64];  // cells x k  (16KB)
    __shared__ __align__(16) __half Bs[128 * 64];  // batch x k  (16KB)
    const int tid = threadIdx.x;
    int orig = blockIdx.y * gridDim.x + blockIdx.x;
    int wgid = xcd_swz(orig, 8 * NT);
    const int b0 = (wgid & 7) * 128;
    const int c0 = (wgid >> 3) * 128;
    const int tile = wgid >> 3;
    const int wid = tid >> 6, lane = tid & 63;
    const int wc = wid >> 2;           // 0..1 -> 64 cells
    const int wb = wid & 3;            // 0..3 -> 32 batch
    const int g4 = lane >> 4, l16 = lane & 15;

    f32x4 acc[4][2] = {};

    for (int k0 = 0; k0 < D_; k0 += 64) {
        if (k0) __syncthreads();
        #pragma unroll
        for (int r = 0; r < 2; ++r) {
            int f = tid + r * 512;        // [0,1024): 128 rows x 8 16B-units
            int row = f >> 3, u = f & 7;
            int ug = (u ^ (row & 7)) * 8;
            int cc = c0 + row; if (cc > NC - 1) cc = NC - 1;
            gl_lds16(&wh[(size_t)cc * D_ + k0 + ug], &As[(f & ~63) * 8]);
            gl_lds16(&xh[(size_t)(b0 + row) * D_ + k0 + ug], &Bs[(f & ~63) * 8]);
        }
        __syncthreads();
        #pragma unroll
        for (int kh = 0; kh < 2; ++kh) {
            int ubase = kh * 4 + g4;
            f16x8 bfr[2];
            #pragma unroll
            for (int fn = 0; fn < 2; ++fn) {
                int rowb = wb * 32 + fn * 16 + l16;
                bfr[fn] = *reinterpret_cast<const f16x8*>(&Bs[rowb * 64 + ((ubase ^ (rowb & 7)) * 8)]);
            }
            #pragma unroll
            for (int fm = 0; fm < 4; ++fm) {
                int rowa = wc * 64 + fm * 16 + l16;
                f16x8 af = *reinterpret_cast<const f16x8*>(&As[rowa * 64 + ((ubase ^ (rowa & 7)) * 8)]);
                #pragma unroll
                for (int fn = 0; fn < 2; ++fn)
                    acc[fm][fn] = __builtin_amdgcn_mfma_f32_16x16x32_f16(af, bfr[fn], acc[fm][fn], 0, 0, 0);
            }
        }
    }

    // per-lane (min1,min2) per fn over fm,r; phantom cells predicated out
    ull m1[2] = {~0ull, ~0ull}, m2[2] = {~0ull, ~0ull};
    #pragma unroll
    for (int fm = 0; fm < 4; ++fm) {
        int cb = c0 + wc * 64 + fm * 16 + g4 * 4;
        float4 wn4 = *reinterpret_cast<const float4*>(&wnorm[cb]);  // ws garbage ok for >=NC (masked)
        float wna[4] = {wn4.x, wn4.y, wn4.z, wn4.w};
        #pragma unroll
        for (int fn = 0; fn < 2; ++fn)
            #pragma unroll
            for (int r = 0; r < 4; ++r) {
                float s = wna[r] - 2.0f * acc[fm][fn][r];
                ull p = (cb + r < NC) ? (((ull)fkey(s) << 32) | (unsigned)(cb + r)) : ~0ull;
                merge2(m1[fn], m2[fn], p, ~0ull);
            }
    }
    #pragma unroll
    for (int fn = 0; fn < 2; ++fn) {
        #pragma unroll
        for (int off = 16; off <= 32; off <<= 1) {
            ull o1 = __shfl_xor(m1[fn], off), o2 = __shfl_xor(m2[fn], off);
            merge2(m1[fn], m2[fn], o1, o2);
        }
    }
    __syncthreads();                   // all MFMA LDS reads done before As reuse
    ull* sm1 = (ull*)&As[0];           // [2][128]
    ull* sm2 = sm1 + 256;
    if (g4 == 0) {
        #pragma unroll
        for (int fn = 0; fn < 2; ++fn) {
            int bl = wb * 32 + fn * 16 + l16;
            sm1[wc * 128 + bl] = m1[fn];
            sm2[wc * 128 + bl] = m2[fn];
        }
    }
    __syncthreads();
    if (tid < 128) {
        ull a1 = sm1[tid], a2 = sm2[tid];
        merge2(a1, a2, sm1[128 + tid], sm2[128 + tid]);
        size_t base = (size_t)(b0 + tid) * PKS + tile * 2;
        pkt[base] = a1;
        pkt[base + 1] = a2;
    }
}

// pass 1: merge 79 tile-pairs per sample; certain -> bxy + candN=0;
// else emit candidate tile list + init packed_fix
__global__ __launch_bounds__(128) void k_bmu1(const ull* __restrict__ pkt, int* __restrict__ candN,
                                              int* __restrict__ candTiles, ull* __restrict__ packed_fix,
                                              int2* __restrict__ bxy) {
    __shared__ ull s1[2], s2[2];
    __shared__ int cnt;
    int b = blockIdx.x;
    int tid = threadIdx.x, lane = tid & 63, wv = tid >> 6;

    ull a1 = ~0ull, a2 = ~0ull;
    if (tid < NT) {
        a1 = pkt[(size_t)b * PKS + tid * 2];
        a2 = pkt[(size_t)b * PKS + tid * 2 + 1];
    }
    #pragma unroll
    for (int off = 1; off <= 32; off <<= 1) {
        ull o1 = __shfl_xor(a1, off), o2 = __shfl_xor(a2, off);
        merge2(a1, a2, o1, o2);
    }
    if (lane == 0) { s1[wv] = a1; s2[wv] = a2; }
    __syncthreads();
    a1 = s1[0]; a2 = s2[0];
    merge2(a1, a2, s1[1], s2[1]);
    float f1 = unfkey((unsigned)(a1 >> 32));
    float f2 = unfkey((unsigned)(a2 >> 32));
    if (f2 - f1 >= TAU) {   // uniform branch: identical f1,f2 across block
        if (tid == 0) {
            candN[b] = 0;
            int c = (int)(unsigned)(a1 & 0xffffffffull);
            bxy[b] = make_int2(c / W_, c % W_);
        }
        return;
    }
    if (tid == 0) { cnt = 0; packed_fix[b] = ~0ull; }
    __syncthreads();
    if (tid < NT) {
        ull mt = pkt[(size_t)b * PKS + tid * 2];
        if (unfkey((unsigned)(mt >> 32)) <= f1 + TAU) {
            int p = atomicAdd(&cnt, 1);
            candTiles[b * (NT + 1) + p] = tid;
        }
    }
    __syncthreads();
    if (tid == 0) candN[b] = cnt;      // >= 1 (BMU's own tile qualifies)
}

// pass 2: grid (B_, MAXC); block (b,j) exact-fp32 min over candidate tiles j, j+MAXC, ...
// wave-per-cell coalesced dots; one u64 atomicMin per block (order-independent)
__global__ __launch_bounds__(256) void k_bmu2(const int* __restrict__ candN, const int* __restrict__ candTiles,
                                              const float* __restrict__ x, const float* __restrict__ w,
                                              ull* __restrict__ packed_fix) {
    int b = blockIdx.x, j = blockIdx.y;
    int n = candN[b];
    if (j >= n) return;
    __shared__ ull sb[4];
    int tid = threadIdx.x, lane = tid & 63, wv = tid >> 6;
    float4 xv = *reinterpret_cast<const float4*>(&x[(size_t)b * D_ + lane * 4]);
    ull best = ~0ull;
    for (int ci = j; ci < n; ci += MAXC) {
        int t = candTiles[b * (NT + 1) + ci];
        #pragma unroll 4
        for (int i = wv; i < 128; i += 4) {   // 4 waves x unroll-4 independent streams
            int c = t * 128 + i;
            if (c < NC) {
                float4 wv4 = *reinterpret_cast<const float4*>(&w[(size_t)c * D_ + lane * 4]);
                float p = wv4.x * (wv4.x - 2.0f * xv.x) + wv4.y * (wv4.y - 2.0f * xv.y)
                        + wv4.z * (wv4.z - 2.0f * xv.z) + wv4.w * (wv4.w - 2.0f * xv.w);
                #pragma unroll
                for (int off = 32; off; off >>= 1) p += __shfl_xor(p, off);
                if (lane == 0) {
                    ull pk = ((ull)fkey(p) << 32) | (unsigned)c;
                    best = pk < best ? pk : best;
                }
            }
        }
    }
    if (lane == 0) sb[wv] = best;
    __syncthreads();
    if (tid == 0) {
        best = sb[0];
        #pragma unroll
        for (int k = 1; k < 4; ++k) best = sb[k] < best ? sb[k] : best;
        atomicMin(&packed_fix[b], best);
    }
}

// pass 3: decode flagged samples
__global__ void k_bmu3(const int* __restrict__ candN, const ull* __restrict__ packed_fix,
                       int2* __restrict__ bxy) {
    int b = blockIdx.x * 256 + threadIdx.x;
    if (b < B_ && candN[b] > 0) {
        int c = (int)(unsigned)(packed_fix[b] & 0xffffffffull);
        bxy[b] = make_int2(c / W_, c % W_);
    }
}

// chunked 2-pass suffix scan with separable-Gaussian LDS table
__global__ __launch_bounds__(256) void k_scan(const int2* __restrict__ bxy, const int* __restrict__ ep,
                                              const int* __restrict__ tp, ushort_t* __restrict__ coefT,
                                              float* __restrict__ T) {
    __shared__ float E[W_];
    float lr, inv2r2;
    decay_params(ep, tp, lr, inv2r2);
    if (threadIdx.x < W_) {
        float d = (float)threadIdx.x;
        E[threadIdx.x] = __expf(-d * d * inv2r2);
    }
    __syncthreads();

    int g = blockIdx.x * 256 + threadIdx.x;
    int c = g >> 3, t = g & 7;
    if (c >= NC) return;
    int cy = c / W_, cx = c % W_;
    int base = t * 128;

    float P = 1.0f;
    for (int i = base; i < base + 128; ++i) {
        int2 p = bxy[i];
        int dy = abs(p.x - cy), dx = abs(p.y - cx);
        float a = lr * E[dy] * E[dx];
        P *= (1.0f - a);
    }
    int gbase = (threadIdx.x & 63) & ~7;
    float M = 1.0f;
    #pragma unroll
    for (int k = 1; k < 8; ++k) {
        float pk = __shfl(P, gbase + k, 64);
        if (k > t) M *= pk;
    }
    if (t == 0) T[c] = M * P;

    float s = M;
    for (int seg = 15; seg >= 0; --seg) {
        ushort_t buf[8];
        #pragma unroll
        for (int e = 7; e >= 0; --e) {
            int i = base + seg * 8 + e;
            int2 p = bxy[i];
            int dy = abs(p.x - cy), dx = abs(p.y - cx);
            float a = lr * E[dy] * E[dx];
            buf[e] = f2bf(a * s);
            s *= (1.0f - a);
        }
        *reinterpret_cast<uint4*>(&coefT[(size_t)c * B_ + base + seg * 8]) =
            *reinterpret_cast<uint4*>(buf);
    }
}

// update GEMM via bf16 MFMA, single-buffer gl_lds staging, XCD-swizzled grid
__global__ __launch_bounds__(256) void k_update(const ushort_t* __restrict__ coefT, const ushort_t* __restrict__ xhT,
                                                const float* __restrict__ T, const float* __restrict__ w0,
                                                float* __restrict__ out) {
    __shared__ __align__(16) ushort_t As[64 * 64];
    __shared__ __align__(16) ushort_t Bs[64 * 64];
    const int tid = threadIdx.x;
    int orig = blockIdx.y * gridDim.x + blockIdx.x;
    int wgid = xcd_swz(orig, 4 * 157);
    const int d0 = (wgid & 3) * 64;
    const int c0 = (wgid >> 2) * 64;
    const int wid = tid >> 6, lane = tid & 63;
    const int wc = wid >> 1, wd = wid & 1;
    const int g4 = lane >> 4, l16 = lane & 15;

    f32x4 acc[2][2] = {};

    for (int k0 = 0; k0 < B_; k0 += 64) {
        if (k0) __syncthreads();
        #pragma unroll
        for (int r = 0; r < 2; ++r) {
            int f = tid + r * 256;        // [0,512): 64 rows x 8 16B-units
            int row = f >> 3, u = f & 7;
            int ug = (u ^ (row & 7)) * 8;
            int cc = c0 + row; if (cc > NC - 1) cc = NC - 1;
            gl_lds16(&coefT[(size_t)cc * B_ + k0 + ug], &As[(f & ~63) * 8]);
            gl_lds16(&xhT[(size_t)(d0 + row) * B_ + k0 + ug], &Bs[(f & ~63) * 8]);
        }
        __syncthreads();
        #pragma unroll
        for (int kh = 0; kh < 2; ++kh) {
            bf16x8 af[2], bfr[2];
            int ubase = kh * 4 + g4;
            #pragma unroll
            for (int fm = 0; fm < 2; ++fm) {
                int rowa = wc * 32 + fm * 16 + l16;
                af[fm] = *reinterpret_cast<const bf16x8*>(&As[rowa * 64 + ((ubase ^ (rowa & 7)) * 8)]);
                int rowb = wd * 32 + fm * 16 + l16;
                bfr[fm] = *reinterpret_cast<const bf16x8*>(&Bs[rowb * 64 + ((ubase ^ (rowb & 7)) * 8)]);
            }
            #pragma unroll
            for (int fm = 0; fm < 2; ++fm)
                #pragma unroll
                for (int fn = 0; fn < 2; ++fn)
                    acc[fm][fn] = __builtin_amdgcn_mfma_f32_16x16x32_bf16(af[fm], bfr[fn], acc[fm][fn], 0, 0, 0);
        }
    }

    #pragma unroll
    for (int fm = 0; fm < 2; ++fm) {
        #pragma unroll
        for (int r = 0; r < 4; ++r) {
            int c = c0 + wc * 32 + fm * 16 + g4 * 4 + r;
            if (c < NC) {
                float t = T[c];
                #pragma unroll
                for (int fn = 0; fn < 2; ++fn) {
                    int d = d0 + wd * 32 + fn * 16 + l16;
                    out[(size_t)c * D_ + d] = fmaf(t, w0[(size_t)c * D_ + d], acc[fm][fn][r]);
                }
            }
        }
    }
}

// ---------- tiny-ws fallback path ----------
__global__ void k_initfix(ull* packed_fix) {
    int i = blockIdx.x * 256 + threadIdx.x;
    if (i < B_) packed_fix[i] = ~0ull;
}
__global__ __launch_bounds__(256) void k_exact_bmu(const float* __restrict__ x, const float* __restrict__ w,
                                                   ull* __restrict__ packed_fix) {
    int b = blockIdx.x;
    int wid = threadIdx.x >> 6, lane = threadIdx.x & 63;
    float4 xv = *reinterpret_cast<const float4*>(&x[(size_t)b * D_ + lane * 4]);
    ull best = ~0ull;
    for (int c = wid; c < NC; c += 4) {
        float4 wv = *reinterpret_cast<const float4*>(&w[(size_t)c * D_ + lane * 4]);
        float p = wv.x * (wv.x - 2.0f * xv.x) + wv.y * (wv.y - 2.0f * xv.y)
                + wv.z * (wv.z - 2.0f * xv.z) + wv.w * (wv.w - 2.0f * xv.w);
        #pragma unroll
        for (int off = 32; off; off >>= 1) p += __shfl_xor(p, off);
        if (lane == 0) {
            ull pk = ((ull)fkey(p) << 32) | (unsigned)c;
            best = pk < best ? pk : best;
        }
    }
    if (lane == 0) atomicMin(&packed_fix[b], best);
}
__global__ void k_decode_force(const ull* __restrict__ packed_fix, float2* __restrict__ xy) {
    int i = blockIdx.x * 256 + threadIdx.x;
    if (i < B_) {
        int c = (int)(unsigned)(packed_fix[i] & 0xffffffffull);
        xy[i] = make_float2((float)(c / W_), (float)(c % W_));
    }
}
__global__ __launch_bounds__(256) void k_update_fallback(const float* __restrict__ x, const float* __restrict__ w0,
                                                         const float2* __restrict__ xy, const int* ep, const int* tp,
                                                         float* __restrict__ out) {
    int c = blockIdx.x;
    int d = threadIdx.x;
    float cyf = (float)(c / W_), cxf = (float)(c % W_);
    float lr, inv2r2;
    decay_params(ep, tp, lr, inv2r2);
    float acc = w0[(size_t)c * D_ + d];
    for (int i = 0; i < B_; ++i) {
        float2 p = xy[i];
        float dy = p.x - cyf, dx = p.y - cxf;
        float a = lr * __expf(-(dy * dy + dx * dx) * inv2r2);
        acc = fmaf(a, x[(size_t)i * D_ + d] - acc, acc);
    }
    out[(size_t)c * D_ + d] = acc;
}

extern "C" void kernel_launch(void* const* d_in, const int* in_sizes, int n_in,
                              void* d_out, int out_size, void* d_ws, size_t ws_size,
                              hipStream_t stream) {
    const float* x = (const float*)d_in[0];
    const float* w = (const float*)d_in[1];
    const int* ep = (const int*)d_in[2];
    const int* tp = (const int*)d_in[3];
    float* out = (float*)d_out;

    char* ws = (char*)d_ws;
    ull* packed_fix = (ull*)(ws + 8192);             // 8KB    @ 8K
    int2* bxy       = (int2*)(ws + 16384);           // 8KB    @ 16K
    float2* xyf     = (float2*)(ws + 16384);         // (fallback alias)
    float* T        = (float*)(ws + 24576);          // 40KB   @ 24K
    float* wnorm    = (float*)(ws + 65536);          // 40.5KB @ 64K
    ushort_t* xhT   = (ushort_t*)(ws + 131072);      // 512KB  @ 128K
    __half* xh      = (__half*)(ws + 655360);        // 512KB
    __half* wh      = (__half*)(ws + 1179648);       // 5.12MB
    ushort_t* coefT = (ushort_t*)(ws + 6553600);     // 20.48MB
    ull* pkt        = (ull*)(ws + 27262976);         // 1024*160*8 = 1.31MB -> ends 28573696
    int* candN      = (int*)(ws + 28573696);         // 4KB
    int* candTiles  = (int*)(ws + 28577792);         // 1024*80*4 = 320KB
    size_t required = 28577792 + (size_t)B_ * (NT + 1) * 4;  // ~28.9MB

    if (ws_size >= required) {
        k_prep<<<NC / 4 + 64, 256, 0, stream>>>(w, x, wh, wnorm, xh, xhT);
        k_scores_mfma<<<dim3(8, NT), 512, 0, stream>>>(wh, xh, wnorm, pkt);
        k_bmu1<<<B_, 128, 0, stream>>>(pkt, candN, candTiles, packed_fix, bxy);
        k_bmu2<<<dim3(B_, MAXC), 256, 0, stream>>>(candN, candTiles, x, w, packed_fix);
        k_bmu3<<<4, 256, 0, stream>>>(candN, packed_fix, bxy);
        k_scan<<<(NC * 8 + 255) / 256, 256, 0, stream>>>(bxy, ep, tp, coefT, T);
        k_update<<<dim3(4, 157), 256, 0, stream>>>(coefT, xhT, T, w, out);
    } else {
        k_initfix<<<4, 256, 0, stream>>>(packed_fix);
        k_exact_bmu<<<B_, 256, 0, stream>>>(x, w, packed_fix);
        k_decode_force<<<4, 256, 0, stream>>>(packed_fix, xyf);
        k_update_fallback<<<NC, 256, 0, stream>>>(x, w, xyf, ep, tp, out);
    }
}